// Round 7
// baseline (90.284 us; speedup 1.0000x reference)
//
#include <hip/hip_runtime.h>
#include <hip/hip_bf16.h>

// MoE gate (DeepSeek-V2 style): logits = X @ W^T, softmax, group-limited
// top-3-of-8 groups, top-6 experts, normalized weights (sorted desc).
//
// X: [T=32768, H=2048] fp32   W: [64, 2048] fp32   out: [T, 6] fp32
//
// Precision: fp32 = hi+mid+lo bf16 (EXACT truncation split); 6 MFMA passes
// (hh, hm, mh, hl, lh, mm) -> ~1e-7 logit error (verified r2-r6, absmax 2e-3).
//
// Round-7 change vs r6 (79.7us): TLP instead of deeper ILP.
//  - 256-thr blocks (4 waves), 64 tokens/block -> 512 blocks = 2 blocks/CU,
//    4 waves/SIMD (was 2). Two blocks per CU are barrier-independent ->
//    LDS-burst and MFMA phases of different blocks overlap.
//  - K-chunks back to 64 (2 steps), LDS 2x24KB = 48KB/block so 2 blocks fit.
//  - A-ring 2-deep; B-stage 2 units/wave; tally ~105 VGPR -> fits the
//    128-reg cap of __launch_bounds__(256,4) WITHOUT r3's spill.
//  - Unchanged: B (L2-hot) staged to LDS, issue-early/write-late; A stream
//    never vmcnt-drained; lane*16B LDS slots (0 bank conflicts).

#define HD 2048
#define NE 64
#define NCH 32       // K-chunks of 64
#define SPC 2        // MFMA-steps (K=32) per chunk
#define BUFB 24576   // bytes per LDS B buffer (2 steps * 3 splits * 4KB)

typedef __attribute__((ext_vector_type(4))) float f4;
typedef __attribute__((ext_vector_type(8))) short s8;
typedef __attribute__((ext_vector_type(4))) short s4;
typedef __attribute__((ext_vector_type(4))) float accv;
typedef unsigned short u16;

// Exact 3-way split of fp32 into hi/mid/lo bf16 (truncation; residuals exact).
__device__ __forceinline__ void split4(const f4 v, s4& h, s4& m, s4& l) {
  #pragma unroll
  for (int i = 0; i < 4; ++i) {
    float a = v[i];
    unsigned u = __builtin_bit_cast(unsigned, a);
    h[i] = (short)(u >> 16);
    float r1 = a - __builtin_bit_cast(float, u & 0xffff0000u);
    unsigned u1 = __builtin_bit_cast(unsigned, r1);
    m[i] = (short)(u1 >> 16);
    float r2 = r1 - __builtin_bit_cast(float, u1 & 0xffff0000u);
    l[i] = (short)(__builtin_bit_cast(unsigned, r2) >> 16);
  }
}

__device__ __forceinline__ void split8(const f4 v0, const f4 v1, s8& h, s8& m, s8& l) {
  s4 h0, m0, l0, h1, m1, l1;
  split4(v0, h0, m0, l0);
  split4(v1, h1, m1, l1);
  #pragma unroll
  for (int i = 0; i < 4; ++i) {
    h[i] = h0[i]; h[i + 4] = h1[i];
    m[i] = m0[i]; m[i + 4] = m1[i];
    l[i] = l0[i]; l[i + 4] = l1[i];
  }
}

// ---- kernel 1: split gate weights fp32 -> {hi,mid,lo} bf16 in d_ws --------
__global__ __launch_bounds__(256) void cvtW3(const float* __restrict__ Wf,
                                             u16* __restrict__ Wh,
                                             u16* __restrict__ Wm,
                                             u16* __restrict__ Wl) {
  int i = (blockIdx.x * 256 + threadIdx.x) * 8;  // 64 blocks cover 131072
  f4 v0 = *(const f4*)(Wf + i);
  f4 v1 = *(const f4*)(Wf + i + 4);
  s8 h, m, l;
  split8(v0, v1, h, m, l);
  *(s8*)((short*)Wh + i) = h;
  *(s8*)((short*)Wm + i) = m;
  *(s8*)((short*)Wl + i) = l;
}

// ---- kernel 2: fused gate ---------------------------------------------------
template <bool PRE>
__global__ __launch_bounds__(256, 4) void gateL(
    const float* __restrict__ X, const float* __restrict__ Wf,
    const u16* __restrict__ Wh, const u16* __restrict__ Wm,
    const u16* __restrict__ Wl, float* __restrict__ out) {
  __shared__ __align__(16) unsigned char smem[2 * BUFB];  // 48 KB

  const int tid = threadIdx.x;
  const int lane = tid & 63;
  const int w = tid >> 6;      // wave 0..3 -> owns tokens tok0 + w*16 ..
  const int ec = lane & 15;    // token row (A) / expert col (B)
  const int kg = lane >> 4;    // 0..3 (8 consecutive k)
  const int tok0 = blockIdx.x * 64;

  // A stream: this wave's 16 token rows
  const float* pA = X + (size_t)(tok0 + w * 16 + ec) * HD + kg * 8;

  // staging roles: wave w stages units u=2w, 2w+1; unit u = (sh=u>>2, sg=u&3)
  const int u0 = 2 * w, u1 = 2 * w + 1;
  const int sh0 = u0 >> 2, sg0 = u0 & 3;
  const int sh1 = u1 >> 2, sg1 = u1 & 3;
  const size_t wsrc0 = (size_t)(sg0 * 16 + ec) * HD + sh0 * 32 + kg * 8;
  const size_t wsrc1 = (size_t)(sg1 * 16 + ec) * HD + sh1 * 32 + kg * 8;
  // LDS dst byte offset: ((sh*3+split)*4+sg)*1024 + lane*16   (+4096/split)
  const int sdst0 = (sh0 * 12 + sg0) * 1024 + lane * 16;
  const int sdst1 = (sh1 * 12 + sg1) * 1024 + lane * 16;

  accv acc[4];
  #pragma unroll
  for (int f = 0; f < 4; ++f) acc[f] = (accv){0.f, 0.f, 0.f, 0.f};

  f4 ar[SPC][2];  // A raw ring, 2-step lookahead (static indices only)

  // --- prologue: stage chunk 0 into buf0; prefetch A steps 0..1 ---
  {
    s8 th, tm, tl;
    f4 r0, r1;
    if constexpr (PRE) {
      th = *(const s8*)(Wh + wsrc0);
      tm = *(const s8*)(Wm + wsrc0);
      tl = *(const s8*)(Wl + wsrc0);
    } else {
      r0 = *(const f4*)(Wf + wsrc0);
      r1 = *(const f4*)(Wf + wsrc0 + 4);
      split8(r0, r1, th, tm, tl);
    }
    unsigned char* d = smem + sdst0;
    *(s8*)(d) = th;
    *(s8*)(d + 4096) = tm;
    *(s8*)(d + 8192) = tl;
    if constexpr (PRE) {
      th = *(const s8*)(Wh + wsrc1);
      tm = *(const s8*)(Wm + wsrc1);
      tl = *(const s8*)(Wl + wsrc1);
    } else {
      r0 = *(const f4*)(Wf + wsrc1);
      r1 = *(const f4*)(Wf + wsrc1 + 4);
      split8(r0, r1, th, tm, tl);
    }
    d = smem + sdst1;
    *(s8*)(d) = th;
    *(s8*)(d + 4096) = tm;
    *(s8*)(d + 8192) = tl;
  }
  #pragma unroll
  for (int st = 0; st < SPC; ++st) {
    ar[st][0] = *(const f4*)(pA + st * 32);
    ar[st][1] = *(const f4*)(pA + st * 32 + 4);
  }
  asm volatile("s_waitcnt lgkmcnt(0)");
  __builtin_amdgcn_s_barrier();
  __builtin_amdgcn_sched_barrier(0);

  // --- main loop: 32 chunks of K=64 (2 MFMA-steps each) ---
  for (int c = 0; c < NCH; ++c) {
    const unsigned char* rb = smem + (c & 1) * BUFB;
    unsigned char* wb = smem + ((c + 1) & 1) * BUFB;
    const bool do_stage = (c + 1 < NCH);

    // issue next-chunk B loads NOW (written to LDS after compute: T14 split)
    s8 th0, tm0, tl0, th1, tm1, tl1;
    f4 q00, q01, q10, q11;
    if (do_stage) {
      const size_t o0 = wsrc0 + (size_t)(c + 1) * 64;
      const size_t o1 = wsrc1 + (size_t)(c + 1) * 64;
      if constexpr (PRE) {
        th0 = *(const s8*)(Wh + o0);
        tm0 = *(const s8*)(Wm + o0);
        tl0 = *(const s8*)(Wl + o0);
        th1 = *(const s8*)(Wh + o1);
        tm1 = *(const s8*)(Wm + o1);
        tl1 = *(const s8*)(Wl + o1);
      } else {
        q00 = *(const f4*)(Wf + o0);
        q01 = *(const f4*)(Wf + o0 + 4);
        q10 = *(const f4*)(Wf + o1);
        q11 = *(const f4*)(Wf + o1 + 4);
      }
    }

    #pragma unroll
    for (int st = 0; st < SPC; ++st) {
      const int t = c * SPC + st;
      s8 ah, am, al;
      split8(ar[st][0], ar[st][1], ah, am, al);
      const int tn = (t + SPC < 64) ? (t + SPC) : 63;  // clamp; dup harmless
      ar[st][0] = *(const f4*)(pA + tn * 32);
      ar[st][1] = *(const f4*)(pA + tn * 32 + 4);
      #pragma unroll
      for (int f = 0; f < 4; ++f) {
        const unsigned char* bp = rb + st * 12288 + f * 1024 + lane * 16;
        s8 bh = *(const s8*)(bp);
        s8 bm = *(const s8*)(bp + 4096);
        s8 bl = *(const s8*)(bp + 8192);
        acc[f] = __builtin_amdgcn_mfma_f32_16x16x32_bf16(ah, bh, acc[f], 0, 0, 0);
        acc[f] = __builtin_amdgcn_mfma_f32_16x16x32_bf16(ah, bm, acc[f], 0, 0, 0);
        acc[f] = __builtin_amdgcn_mfma_f32_16x16x32_bf16(am, bh, acc[f], 0, 0, 0);
        acc[f] = __builtin_amdgcn_mfma_f32_16x16x32_bf16(ah, bl, acc[f], 0, 0, 0);
        acc[f] = __builtin_amdgcn_mfma_f32_16x16x32_bf16(al, bh, acc[f], 0, 0, 0);
        acc[f] = __builtin_amdgcn_mfma_f32_16x16x32_bf16(am, bm, acc[f], 0, 0, 0);
      }
    }

    // write staged B (loads have had 2 steps + boundary to land)
    if (do_stage) {
      if constexpr (!PRE) {
        split8(q00, q01, th0, tm0, tl0);
        split8(q10, q11, th1, tm1, tl1);
      }
      unsigned char* d = wb + sdst0;
      *(s8*)(d) = th0;
      *(s8*)(d + 4096) = tm0;
      *(s8*)(d + 8192) = tl0;
      d = wb + sdst1;
      *(s8*)(d) = th1;
      *(s8*)(d + 4096) = tm1;
      *(s8*)(d + 8192) = tl1;
    }
    // boundary: LDS-only drain; A vmcnt stream NEVER drained
    __builtin_amdgcn_sched_barrier(0);
    asm volatile("s_waitcnt lgkmcnt(0)");
    __builtin_amdgcn_s_barrier();
    __builtin_amdgcn_sched_barrier(0);
  }

  // --- epilogue: per-wave logit scatter (own region, no barrier needed) ---
  float* lf = (float*)smem + w * 1088;  // 16 tok x 68 floats
  #pragma unroll
  for (int f = 0; f < 4; ++f)
    #pragma unroll
    for (int r = 0; r < 4; ++r)
      lf[(kg * 4 + r) * 68 + f * 16 + ec] = acc[f][r];

  if (lane < 16) {
    float v[64];
    #pragma unroll
    for (int i = 0; i < 16; ++i) {
      f4 q = *(const f4*)(lf + lane * 68 + 4 * i);
      v[4 * i + 0] = q.x; v[4 * i + 1] = q.y;
      v[4 * i + 2] = q.z; v[4 * i + 3] = q.w;
    }
    // group maxes on logits (softmax monotonic -> same selection)
    float gm[8];
    #pragma unroll
    for (int g = 0; g < 8; ++g) {
      float mx = v[g * 8];
      #pragma unroll
      for (int j = 1; j < 8; ++j) mx = fmaxf(mx, v[g * 8 + j]);
      gm[g] = mx;
    }
    // top-3 groups, ties -> lowest index (matches lax.top_k)
    unsigned selmask = 0u;
    #pragma unroll
    for (int itg = 0; itg < 3; ++itg) {
      float best = gm[0];
      #pragma unroll
      for (int g = 1; g < 8; ++g) best = fmaxf(best, gm[g]);
      int bi = 7;
      #pragma unroll
      for (int g = 6; g >= 0; --g)
        if (gm[g] == best) bi = g;
      selmask |= (1u << bi);
      #pragma unroll
      for (int g = 0; g < 8; ++g) gm[g] = (g == bi) ? -3.0e38f : gm[g];
    }
    // top-6 of selected-group logits, branchless insertion network (desc)
    float t0 = -3.0e38f, t1 = -3.0e38f, t2 = -3.0e38f;
    float t3 = -3.0e38f, t4 = -3.0e38f, t5 = -3.0e38f;
    #pragma unroll
    for (int g = 0; g < 8; ++g) {
      const bool sel = (selmask >> g) & 1u;
      #pragma unroll
      for (int j = 0; j < 8; ++j) {
        float x = sel ? v[g * 8 + j] : -3.0e38f;
        float mm;
        mm = fmaxf(t0, x); x = fminf(t0, x); t0 = mm;
        mm = fmaxf(t1, x); x = fminf(t1, x); t1 = mm;
        mm = fmaxf(t2, x); x = fminf(t2, x); t2 = mm;
        mm = fmaxf(t3, x); x = fminf(t3, x); t3 = mm;
        mm = fmaxf(t4, x); x = fminf(t4, x); t4 = mm;
        t5 = fmaxf(t5, x);
      }
    }
    // normalized softmax over the selected 6 (global denom cancels exactly)
    float e0 = 1.0f;
    float e1 = __expf(t1 - t0);
    float e2 = __expf(t2 - t0);
    float e3 = __expf(t3 - t0);
    float e4 = __expf(t4 - t0);
    float e5 = __expf(t5 - t0);
    float sum = e0 + e1 + e2 + e3 + e4 + e5;
    float inv = 1.0f / sum;
    float* op = out + (size_t)(tok0 + w * 16 + lane) * 6;
    op[0] = e0 * inv; op[1] = e1 * inv; op[2] = e2 * inv;
    op[3] = e3 * inv; op[4] = e4 * inv; op[5] = e5 * inv;
  }
}

extern "C" void kernel_launch(void* const* d_in, const int* in_sizes, int n_in,
                              void* d_out, int out_size, void* d_ws, size_t ws_size,
                              hipStream_t stream) {
  const float* X = (const float*)d_in[0];
  const float* Wf = (const float*)d_in[1];
  float* out = (float*)d_out;
  const int T = in_sizes[0] / HD;  // 32768
  const int nblk = T / 64;         // 512 blocks of 256 threads (4 waves)

  const size_t need = (size_t)NE * HD * sizeof(u16);  // 256 KB per split
  if (ws_size >= 3 * need) {
    u16* Whi = (u16*)d_ws;
    u16* Wmi = Whi + (size_t)NE * HD;
    u16* Wlo = Wmi + (size_t)NE * HD;
    cvtW3<<<dim3(64), dim3(256), 0, stream>>>(Wf, Whi, Wmi, Wlo);
    gateL<true><<<dim3(nblk), dim3(256), 0, stream>>>(X, Wf, Whi, Wmi, Wlo, out);
  } else {
    gateL<false><<<dim3(nblk), dim3(256), 0, stream>>>(X, Wf, nullptr, nullptr, nullptr, out);
  }
}

// Round 8
// 84.357 us; speedup vs baseline: 1.0703x; 1.0703x over previous
//
#include <hip/hip_runtime.h>
#include <hip/hip_bf16.h>

// MoE gate (DeepSeek-V2 style): logits = X @ W^T, softmax, group-limited
// top-3-of-8 groups, top-6 experts, normalized weights (sorted desc).
//
// X: [T=32768, H=2048] fp32   W: [64, 2048] fp32   out: [T, 6] fp32
//
// Precision: fp32 = hi+mid+lo bf16 (EXACT truncation split); 6 MFMA passes
// (hh, hm, mh, hl, lh, mm) -> ~1e-7 logit error (verified r2-r7, absmax 2e-3).
//
// Round-8: SPLIT-K x2 across paired blocks (fixes r7's bundled regressions).
//  - gateK: 512 blocks x 512 thr (8 waves); block b: tokens (b>>1)*128,
//    K-half (b&1)*1024. 2 blocks/CU -> 16 waves/CU = 4/SIMD TLP.
//  - Per-CU W-stage traffic unchanged vs r6 (2 half-K blocks = 1 full-K);
//    per-CU LDS-read traffic unchanged; A-ring stays 4-deep (static slots
//    via 2-chunk unroll); K-64 chunks -> 48KB LDS so 2 blocks fit.
//  - Partials (2 x T x 64 fp32 = 16.8MB) in d_ws; gateR reduces + epilogue
//    (coalesced loads, LDS transpose pad-68, all 64 lanes productive).
//  - Fallback r6 single-kernel path kept for small ws_size.

#define HD 2048
#define NE 64
#define TT 32768

// gateK geometry (K-64 chunks)
#define KBUFB 24576  // 2 steps * 3 splits * 4 groups * 1024 B
// gateL fallback geometry (r6: K-128 chunks)
#define NCH 16
#define SPC 4
#define BUFB 49152

typedef __attribute__((ext_vector_type(4))) float f4;
typedef __attribute__((ext_vector_type(8))) short s8;
typedef __attribute__((ext_vector_type(4))) short s4;
typedef __attribute__((ext_vector_type(4))) float accv;
typedef unsigned short u16;

struct B3 { s8 h, m, l; };

// Exact 3-way split of fp32 into hi/mid/lo bf16 (truncation; residuals exact).
__device__ __forceinline__ void split4(const f4 v, s4& h, s4& m, s4& l) {
  #pragma unroll
  for (int i = 0; i < 4; ++i) {
    float a = v[i];
    unsigned u = __builtin_bit_cast(unsigned, a);
    h[i] = (short)(u >> 16);
    float r1 = a - __builtin_bit_cast(float, u & 0xffff0000u);
    unsigned u1 = __builtin_bit_cast(unsigned, r1);
    m[i] = (short)(u1 >> 16);
    float r2 = r1 - __builtin_bit_cast(float, u1 & 0xffff0000u);
    l[i] = (short)(__builtin_bit_cast(unsigned, r2) >> 16);
  }
}

__device__ __forceinline__ void split8(const f4 v0, const f4 v1, s8& h, s8& m, s8& l) {
  s4 h0, m0, l0, h1, m1, l1;
  split4(v0, h0, m0, l0);
  split4(v1, h1, m1, l1);
  #pragma unroll
  for (int i = 0; i < 4; ++i) {
    h[i] = h0[i]; h[i + 4] = h1[i];
    m[i] = m0[i]; m[i + 4] = m1[i];
    l[i] = l0[i]; l[i + 4] = l1[i];
  }
}

__device__ __forceinline__ accv mfma6(s8 ah, s8 am, s8 al, const B3& b, accv t) {
  t = __builtin_amdgcn_mfma_f32_16x16x32_bf16(ah, b.h, t, 0, 0, 0);
  t = __builtin_amdgcn_mfma_f32_16x16x32_bf16(ah, b.m, t, 0, 0, 0);
  t = __builtin_amdgcn_mfma_f32_16x16x32_bf16(am, b.h, t, 0, 0, 0);
  t = __builtin_amdgcn_mfma_f32_16x16x32_bf16(ah, b.l, t, 0, 0, 0);
  t = __builtin_amdgcn_mfma_f32_16x16x32_bf16(al, b.h, t, 0, 0, 0);
  t = __builtin_amdgcn_mfma_f32_16x16x32_bf16(am, b.m, t, 0, 0, 0);
  return t;
}

// Shared epilogue: v[64] logits -> top-3 groups -> top-6 -> normalized weights.
__device__ __forceinline__ void epilogue64(const float* v, float* op) {
  float gm[8];
  #pragma unroll
  for (int g = 0; g < 8; ++g) {
    float mx = v[g * 8];
    #pragma unroll
    for (int j = 1; j < 8; ++j) mx = fmaxf(mx, v[g * 8 + j]);
    gm[g] = mx;
  }
  unsigned selmask = 0u;
  #pragma unroll
  for (int itg = 0; itg < 3; ++itg) {
    float best = gm[0];
    #pragma unroll
    for (int g = 1; g < 8; ++g) best = fmaxf(best, gm[g]);
    int bi = 7;
    #pragma unroll
    for (int g = 6; g >= 0; --g)
      if (gm[g] == best) bi = g;
    selmask |= (1u << bi);
    #pragma unroll
    for (int g = 0; g < 8; ++g) gm[g] = (g == bi) ? -3.0e38f : gm[g];
  }
  float t0 = -3.0e38f, t1 = -3.0e38f, t2 = -3.0e38f;
  float t3 = -3.0e38f, t4 = -3.0e38f, t5 = -3.0e38f;
  #pragma unroll
  for (int g = 0; g < 8; ++g) {
    const bool sel = (selmask >> g) & 1u;
    #pragma unroll
    for (int j = 0; j < 8; ++j) {
      float x = sel ? v[g * 8 + j] : -3.0e38f;
      float mm;
      mm = fmaxf(t0, x); x = fminf(t0, x); t0 = mm;
      mm = fmaxf(t1, x); x = fminf(t1, x); t1 = mm;
      mm = fmaxf(t2, x); x = fminf(t2, x); t2 = mm;
      mm = fmaxf(t3, x); x = fminf(t3, x); t3 = mm;
      mm = fmaxf(t4, x); x = fminf(t4, x); t4 = mm;
      t5 = fmaxf(t5, x);
    }
  }
  float e0 = 1.0f;
  float e1 = __expf(t1 - t0);
  float e2 = __expf(t2 - t0);
  float e3 = __expf(t3 - t0);
  float e4 = __expf(t4 - t0);
  float e5 = __expf(t5 - t0);
  float sum = e0 + e1 + e2 + e3 + e4 + e5;
  float inv = 1.0f / sum;
  op[0] = e0 * inv; op[1] = e1 * inv; op[2] = e2 * inv;
  op[3] = e3 * inv; op[4] = e4 * inv; op[5] = e5 * inv;
}

// ---- kernel 1: split gate weights fp32 -> {hi,mid,lo} bf16 in d_ws --------
__global__ __launch_bounds__(256) void cvtW3(const float* __restrict__ Wf,
                                             u16* __restrict__ Wh,
                                             u16* __restrict__ Wm,
                                             u16* __restrict__ Wl) {
  int i = (blockIdx.x * 256 + threadIdx.x) * 8;  // 64 blocks cover 131072
  f4 v0 = *(const f4*)(Wf + i);
  f4 v1 = *(const f4*)(Wf + i + 4);
  s8 h, m, l;
  split8(v0, v1, h, m, l);
  *(s8*)((short*)Wh + i) = h;
  *(s8*)((short*)Wm + i) = m;
  *(s8*)((short*)Wl + i) = l;
}

// ---- kernel 2a: split-K GEMM half, partials to ws --------------------------
#define GK_SYNC()                          \
  do {                                     \
    __builtin_amdgcn_sched_barrier(0);     \
    asm volatile("s_waitcnt lgkmcnt(0)");  \
    __builtin_amdgcn_s_barrier();          \
    __builtin_amdgcn_sched_barrier(0);     \
  } while (0)

#define GK_STEP(T_, SLOT_, STC_)                                              \
  do {                                                                        \
    s8 ah, am, al;                                                            \
    split8(ar[SLOT_][0], ar[SLOT_][1], ah, am, al);                           \
    const int tn_ = ((T_) + 4 < 32) ? ((T_) + 4) : 31;                        \
    ar[SLOT_][0] = *(const f4*)(pA + tn_ * 32);                               \
    ar[SLOT_][1] = *(const f4*)(pA + tn_ * 32 + 4);                           \
    _Pragma("unroll") for (int f_ = 0; f_ < 4; ++f_) {                        \
      const unsigned char* bp_ = rb + (STC_)*12288 + f_ * 1024 + lane * 16;   \
      B3 b_;                                                                  \
      b_.h = *(const s8*)(bp_);                                               \
      b_.m = *(const s8*)(bp_ + 4096);                                        \
      b_.l = *(const s8*)(bp_ + 8192);                                        \
      acc[f_] = mfma6(ah, am, al, b_, acc[f_]);                               \
    }                                                                         \
  } while (0)

__global__ __launch_bounds__(512, 4) void gateK(
    const float* __restrict__ X, const u16* __restrict__ Wh,
    const u16* __restrict__ Wm, const u16* __restrict__ Wl,
    float* __restrict__ part) {
  __shared__ __align__(16) unsigned char smem[2 * KBUFB];  // 48 KB

  const int tid = threadIdx.x;
  const int lane = tid & 63;
  const int w = tid >> 6;    // wave 0..7
  const int ec = lane & 15;  // token row (A) / expert col (B)
  const int kg = lane >> 4;  // 0..3 (8 consecutive k)
  const int kq = blockIdx.x & 1;
  const int tok0 = (blockIdx.x >> 1) * 128;
  const int kbase = kq * 1024;

  const float* pA = X + (size_t)(tok0 + w * 16 + ec) * HD + kbase + kg * 8;

  // staging: wave w stages unit (sh = w>>2, sg = w&3), all 3 splits
  const int sh = w >> 2, sg = w & 3;
  const size_t wsrc = (size_t)(sg * 16 + ec) * HD + kbase + sh * 32 + kg * 8;
  const int sdst = (sh * 12 + sg) * 1024 + lane * 16;  // split s: +s*4096

  accv acc[4];
  #pragma unroll
  for (int f = 0; f < 4; ++f) acc[f] = (accv){0.f, 0.f, 0.f, 0.f};

  f4 ar[4][2];  // A ring, 4-deep, static slots

  // prologue: stage chunk 0 -> buf0; prefetch A steps 0..3
  {
    s8 th = *(const s8*)(Wh + wsrc);
    s8 tm = *(const s8*)(Wm + wsrc);
    s8 tl = *(const s8*)(Wl + wsrc);
    unsigned char* d = smem + sdst;
    *(s8*)(d) = th;
    *(s8*)(d + 4096) = tm;
    *(s8*)(d + 8192) = tl;
  }
  #pragma unroll
  for (int s = 0; s < 4; ++s) {
    ar[s][0] = *(const f4*)(pA + s * 32);
    ar[s][1] = *(const f4*)(pA + s * 32 + 4);
  }
  GK_SYNC();

  // 16 chunks of K=64 (2 steps each), unrolled in pairs for static ring slots
  for (int cc = 0; cc < 8; ++cc) {
    {  // chunk c0 = 2cc : read buf0, stage chunk c0+1 -> buf1
      const unsigned char* rb = smem;
      const size_t o = wsrc + (size_t)(2 * cc + 1) * 64;
      s8 th = *(const s8*)(Wh + o);
      s8 tm = *(const s8*)(Wm + o);
      s8 tl = *(const s8*)(Wl + o);
      GK_STEP(4 * cc + 0, 0, 0);
      GK_STEP(4 * cc + 1, 1, 1);
      unsigned char* d = smem + KBUFB + sdst;
      *(s8*)(d) = th;
      *(s8*)(d + 4096) = tm;
      *(s8*)(d + 8192) = tl;
      GK_SYNC();
    }
    {  // chunk c1 = 2cc+1 : read buf1, stage chunk c1+1 -> buf0
      const unsigned char* rb = smem + KBUFB;
      const bool dost = (cc < 7);
      s8 th, tm, tl;
      if (dost) {
        const size_t o = wsrc + (size_t)(2 * cc + 2) * 64;
        th = *(const s8*)(Wh + o);
        tm = *(const s8*)(Wm + o);
        tl = *(const s8*)(Wl + o);
      }
      GK_STEP(4 * cc + 2, 2, 0);
      GK_STEP(4 * cc + 3, 3, 1);
      if (dost) {
        unsigned char* d = smem + sdst;
        *(s8*)(d) = th;
        *(s8*)(d + 4096) = tm;
        *(s8*)(d + 8192) = tl;
      }
      GK_SYNC();
    }
  }

  // partial store: part[(kq*TT + token)*64 + expert]
  float* pp = part + ((size_t)kq * TT + tok0 + w * 16) * 64;
  #pragma unroll
  for (int f = 0; f < 4; ++f)
    #pragma unroll
    for (int r = 0; r < 4; ++r)
      pp[(size_t)(kg * 4 + r) * 64 + f * 16 + ec] = acc[f][r];
}

// ---- kernel 2b: reduce halves + epilogue -----------------------------------
__global__ __launch_bounds__(256) void gateR(const float* __restrict__ part,
                                             float* __restrict__ out) {
  __shared__ float lds[4][64 * 68];  // per-wave 64 tok x 64 logits, pad 68
  const int lane = threadIdx.x & 63;
  const int w = threadIdx.x >> 6;
  const int tok0 = blockIdx.x * 256 + w * 64;
  float* L = lds[w];
  #pragma unroll 4
  for (int r = 0; r < 64; ++r) {  // coalesced: lane = expert
    float a = part[((size_t)tok0 + r) * 64 + lane];
    float b = part[((size_t)TT + tok0 + r) * 64 + lane];
    L[r * 68 + lane] = a + b;
  }
  __syncthreads();
  float v[64];
  #pragma unroll
  for (int i = 0; i < 16; ++i) {
    f4 q = *(const f4*)(L + lane * 68 + 4 * i);
    v[4 * i + 0] = q.x; v[4 * i + 1] = q.y;
    v[4 * i + 2] = q.z; v[4 * i + 3] = q.w;
  }
  epilogue64(v, out + (size_t)(tok0 + lane) * 6);
}

// ---- fallback: r6 single-kernel full-K (79.7us), used if ws too small ------
template <bool PRE>
__global__ __launch_bounds__(512, 2) void gateL(
    const float* __restrict__ X, const float* __restrict__ Wf,
    const u16* __restrict__ Wh, const u16* __restrict__ Wm,
    const u16* __restrict__ Wl, float* __restrict__ out) {
  __shared__ __align__(16) unsigned char smem[2 * BUFB];  // 96 KB

  const int tid = threadIdx.x;
  const int lane = tid & 63;
  const int w = tid >> 6;
  const int ec = lane & 15;
  const int kg = lane >> 4;
  const int tok0 = blockIdx.x * 128;

  const float* pA = X + (size_t)(tok0 + w * 16 + ec) * HD + kg * 8;

  const int u0 = 2 * w, u1 = 2 * w + 1;
  const int sh0 = u0 >> 2, sg0 = u0 & 3;
  const int sh1 = u1 >> 2, sg1 = u1 & 3;
  const size_t wsrc0 = (size_t)(sg0 * 16 + ec) * HD + sh0 * 32 + kg * 8;
  const size_t wsrc1 = (size_t)(sg1 * 16 + ec) * HD + sh1 * 32 + kg * 8;
  const int sdst0 = (sh0 * 12 + sg0) * 1024 + lane * 16;
  const int sdst1 = (sh1 * 12 + sg1) * 1024 + lane * 16;

  accv acc[4];
  #pragma unroll
  for (int f = 0; f < 4; ++f) acc[f] = (accv){0.f, 0.f, 0.f, 0.f};

  f4 ar[SPC][2];

  {
    s8 th, tm, tl;
    f4 r0, r1;
    if constexpr (PRE) {
      th = *(const s8*)(Wh + wsrc0);
      tm = *(const s8*)(Wm + wsrc0);
      tl = *(const s8*)(Wl + wsrc0);
    } else {
      r0 = *(const f4*)(Wf + wsrc0);
      r1 = *(const f4*)(Wf + wsrc0 + 4);
      split8(r0, r1, th, tm, tl);
    }
    unsigned char* d = smem + sdst0;
    *(s8*)(d) = th;
    *(s8*)(d + 4096) = tm;
    *(s8*)(d + 8192) = tl;
    if constexpr (PRE) {
      th = *(const s8*)(Wh + wsrc1);
      tm = *(const s8*)(Wm + wsrc1);
      tl = *(const s8*)(Wl + wsrc1);
    } else {
      r0 = *(const f4*)(Wf + wsrc1);
      r1 = *(const f4*)(Wf + wsrc1 + 4);
      split8(r0, r1, th, tm, tl);
    }
    d = smem + sdst1;
    *(s8*)(d) = th;
    *(s8*)(d + 4096) = tm;
    *(s8*)(d + 8192) = tl;
  }
  #pragma unroll
  for (int st = 0; st < SPC; ++st) {
    ar[st][0] = *(const f4*)(pA + st * 32);
    ar[st][1] = *(const f4*)(pA + st * 32 + 4);
  }
  asm volatile("s_waitcnt lgkmcnt(0)");
  __builtin_amdgcn_s_barrier();
  __builtin_amdgcn_sched_barrier(0);

  for (int c = 0; c < NCH; ++c) {
    const unsigned char* rb = smem + (c & 1) * BUFB;
    unsigned char* wb = smem + ((c + 1) & 1) * BUFB;
    const bool do_stage = (c + 1 < NCH);

    s8 th0, tm0, tl0, th1, tm1, tl1;
    f4 q00, q01, q10, q11;
    if (do_stage) {
      const size_t o0 = wsrc0 + (size_t)(c + 1) * 128;
      const size_t o1 = wsrc1 + (size_t)(c + 1) * 128;
      if constexpr (PRE) {
        th0 = *(const s8*)(Wh + o0);
        tm0 = *(const s8*)(Wm + o0);
        tl0 = *(const s8*)(Wl + o0);
        th1 = *(const s8*)(Wh + o1);
        tm1 = *(const s8*)(Wm + o1);
        tl1 = *(const s8*)(Wl + o1);
      } else {
        q00 = *(const f4*)(Wf + o0);
        q01 = *(const f4*)(Wf + o0 + 4);
        q10 = *(const f4*)(Wf + o1);
        q11 = *(const f4*)(Wf + o1 + 4);
      }
    }

    #pragma unroll
    for (int st = 0; st < SPC; ++st) {
      const int t = c * SPC + st;
      s8 ah, am, al;
      split8(ar[st][0], ar[st][1], ah, am, al);
      const int tn = (t + SPC < 64) ? (t + SPC) : 63;
      ar[st][0] = *(const f4*)(pA + tn * 32);
      ar[st][1] = *(const f4*)(pA + tn * 32 + 4);
      #pragma unroll
      for (int f = 0; f < 4; ++f) {
        const unsigned char* bp = rb + st * 12288 + f * 1024 + lane * 16;
        B3 b_;
        b_.h = *(const s8*)(bp);
        b_.m = *(const s8*)(bp + 4096);
        b_.l = *(const s8*)(bp + 8192);
        acc[f] = mfma6(ah, am, al, b_, acc[f]);
      }
    }

    if (do_stage) {
      if constexpr (!PRE) {
        split8(q00, q01, th0, tm0, tl0);
        split8(q10, q11, th1, tm1, tl1);
      }
      unsigned char* d = wb + sdst0;
      *(s8*)(d) = th0;
      *(s8*)(d + 4096) = tm0;
      *(s8*)(d + 8192) = tl0;
      d = wb + sdst1;
      *(s8*)(d) = th1;
      *(s8*)(d + 4096) = tm1;
      *(s8*)(d + 8192) = tl1;
    }
    __builtin_amdgcn_sched_barrier(0);
    asm volatile("s_waitcnt lgkmcnt(0)");
    __builtin_amdgcn_s_barrier();
    __builtin_amdgcn_sched_barrier(0);
  }

  float* lf = (float*)smem + w * 1088;
  #pragma unroll
  for (int f = 0; f < 4; ++f)
    #pragma unroll
    for (int r = 0; r < 4; ++r)
      lf[(kg * 4 + r) * 68 + f * 16 + ec] = acc[f][r];

  if (lane < 16) {
    float v[64];
    #pragma unroll
    for (int i = 0; i < 16; ++i) {
      f4 q = *(const f4*)(lf + lane * 68 + 4 * i);
      v[4 * i + 0] = q.x; v[4 * i + 1] = q.y;
      v[4 * i + 2] = q.z; v[4 * i + 3] = q.w;
    }
    epilogue64(v, out + (size_t)(tok0 + w * 16 + lane) * 6);
  }
}

extern "C" void kernel_launch(void* const* d_in, const int* in_sizes, int n_in,
                              void* d_out, int out_size, void* d_ws, size_t ws_size,
                              hipStream_t stream) {
  const float* X = (const float*)d_in[0];
  const float* Wf = (const float*)d_in[1];
  float* out = (float*)d_out;
  const int T = in_sizes[0] / HD;  // 32768

  const size_t needW = 3 * (size_t)NE * HD * sizeof(u16);   // 768 KB
  const size_t needP = 2ull * (size_t)T * 64 * sizeof(float);  // 16.78 MB

  if (ws_size >= needW + needP) {
    u16* Whi = (u16*)d_ws;
    u16* Wmi = Whi + (size_t)NE * HD;
    u16* Wlo = Wmi + (size_t)NE * HD;
    float* part = (float*)((char*)d_ws + needW);
    cvtW3<<<dim3(64), dim3(256), 0, stream>>>(Wf, Whi, Wmi, Wlo);
    gateK<<<dim3(T / 64), dim3(512), 0, stream>>>(X, Whi, Wmi, Wlo, part);
    gateR<<<dim3(T / 256), dim3(256), 0, stream>>>(part, out);
  } else if (ws_size >= needW) {
    u16* Whi = (u16*)d_ws;
    u16* Wmi = Whi + (size_t)NE * HD;
    u16* Wlo = Wmi + (size_t)NE * HD;
    cvtW3<<<dim3(64), dim3(256), 0, stream>>>(Wf, Whi, Wmi, Wlo);
    gateL<true><<<dim3(T / 128), dim3(512), 0, stream>>>(X, Wf, Whi, Wmi, Wlo, out);
  } else {
    gateL<false><<<dim3(T / 128), dim3(512), 0, stream>>>(X, Wf, nullptr, nullptr, nullptr, out);
  }
}

// Round 9
// 72.043 us; speedup vs baseline: 1.2532x; 1.1709x over previous
//
#include <hip/hip_runtime.h>
#include <hip/hip_bf16.h>

// MoE gate (DeepSeek-V2 style): logits = X @ W^T, softmax, group-limited
// top-3-of-8 groups, top-6 experts, normalized weights (sorted desc).
//
// X: [T=32768, H=2048] fp32   W: [64, 2048] fp32   out: [T, 6] fp32
//
// Round-9 precision plan: fp32 = hi+lo FP16 (11+11 = 22 mantissa bits; the
// residual split is exact, only the lo*lo term ~2^-22 is dropped). 3 MFMA
// passes (hh, hl, lh) replace r2-r8's 6 bf16 passes. Logit error ~4e-7 --
// same class as fp32 accumulation noise, far inside the ~7e-3 selection-tie
// band (r1 evidence). Halves B LDS reads (12->8/step), MFMA (24->12), LDS
// (96->64KB) on the proven r6 skeleton:
//  - 256 blocks x 512 thr (8 waves), 16 tokens/wave, K-128 chunks (4 steps),
//    A-ring 4-deep direct global->reg (never vmcnt-drained), B (L2-hot)
//    staged to LDS issue-early/write-late, lane*16B slots (0 conflicts),
//    lgkmcnt-only chunk barriers.

#define HD 2048
#define NE 64
#define NCH 16       // K-chunks of 128
#define BUFB 32768   // bytes per LDS B buffer: 4 steps * 2 splits * 4KB

typedef __attribute__((ext_vector_type(4))) float f4;
typedef __attribute__((ext_vector_type(8))) short s8;
typedef __attribute__((ext_vector_type(8))) _Float16 h8;
typedef __attribute__((ext_vector_type(4))) float accv;
typedef unsigned short u16;

// fp32 -> hi/lo fp16 split (RNE; residual exact; dropped term ~2^-22).
__device__ __forceinline__ void split8h(const f4 v0, const f4 v1, s8& h, s8& l) {
  #pragma unroll
  for (int i = 0; i < 8; ++i) {
    float a = (i < 4) ? v0[i] : v1[i - 4];
    _Float16 hh = (_Float16)a;
    float r = a - (float)hh;
    _Float16 ll = (_Float16)r;
    h[i] = __builtin_bit_cast(short, hh);
    l[i] = __builtin_bit_cast(short, ll);
  }
}

__device__ __forceinline__ accv mfma3(s8 ah, s8 al, s8 bh, s8 bl, accv t) {
  h8 AH = __builtin_bit_cast(h8, ah);
  h8 AL = __builtin_bit_cast(h8, al);
  h8 BH = __builtin_bit_cast(h8, bh);
  h8 BL = __builtin_bit_cast(h8, bl);
  t = __builtin_amdgcn_mfma_f32_16x16x32_f16(AH, BH, t, 0, 0, 0);
  t = __builtin_amdgcn_mfma_f32_16x16x32_f16(AH, BL, t, 0, 0, 0);
  t = __builtin_amdgcn_mfma_f32_16x16x32_f16(AL, BH, t, 0, 0, 0);
  return t;
}

// Shared epilogue: v[64] logits -> top-3 groups -> top-6 -> normalized weights.
__device__ __forceinline__ void epilogue64(const float* v, float* op) {
  float gm[8];
  #pragma unroll
  for (int g = 0; g < 8; ++g) {
    float mx = v[g * 8];
    #pragma unroll
    for (int j = 1; j < 8; ++j) mx = fmaxf(mx, v[g * 8 + j]);
    gm[g] = mx;
  }
  unsigned selmask = 0u;
  #pragma unroll
  for (int itg = 0; itg < 3; ++itg) {
    float best = gm[0];
    #pragma unroll
    for (int g = 1; g < 8; ++g) best = fmaxf(best, gm[g]);
    int bi = 7;
    #pragma unroll
    for (int g = 6; g >= 0; --g)
      if (gm[g] == best) bi = g;
    selmask |= (1u << bi);
    #pragma unroll
    for (int g = 0; g < 8; ++g) gm[g] = (g == bi) ? -3.0e38f : gm[g];
  }
  float t0 = -3.0e38f, t1 = -3.0e38f, t2 = -3.0e38f;
  float t3 = -3.0e38f, t4 = -3.0e38f, t5 = -3.0e38f;
  #pragma unroll
  for (int g = 0; g < 8; ++g) {
    const bool sel = (selmask >> g) & 1u;
    #pragma unroll
    for (int j = 0; j < 8; ++j) {
      float x = sel ? v[g * 8 + j] : -3.0e38f;
      float mm;
      mm = fmaxf(t0, x); x = fminf(t0, x); t0 = mm;
      mm = fmaxf(t1, x); x = fminf(t1, x); t1 = mm;
      mm = fmaxf(t2, x); x = fminf(t2, x); t2 = mm;
      mm = fmaxf(t3, x); x = fminf(t3, x); t3 = mm;
      mm = fmaxf(t4, x); x = fminf(t4, x); t4 = mm;
      t5 = fmaxf(t5, x);
    }
  }
  float e0 = 1.0f;
  float e1 = __expf(t1 - t0);
  float e2 = __expf(t2 - t0);
  float e3 = __expf(t3 - t0);
  float e4 = __expf(t4 - t0);
  float e5 = __expf(t5 - t0);
  float sum = e0 + e1 + e2 + e3 + e4 + e5;
  float inv = 1.0f / sum;
  op[0] = e0 * inv; op[1] = e1 * inv; op[2] = e2 * inv;
  op[3] = e3 * inv; op[4] = e4 * inv; op[5] = e5 * inv;
}

// ---- kernel 1: split gate weights fp32 -> {hi,lo} fp16 in d_ws ------------
__global__ __launch_bounds__(256) void cvtW2(const float* __restrict__ Wf,
                                             u16* __restrict__ Wh,
                                             u16* __restrict__ Wl) {
  int i = (blockIdx.x * 256 + threadIdx.x) * 8;  // 64 blocks cover 131072
  f4 v0 = *(const f4*)(Wf + i);
  f4 v1 = *(const f4*)(Wf + i + 4);
  s8 h, l;
  split8h(v0, v1, h, l);
  *(s8*)((short*)Wh + i) = h;
  *(s8*)((short*)Wl + i) = l;
}

// ---- kernel 2: fused gate (r6 skeleton, fp16 2-split) ----------------------
template <bool PRE>
__global__ __launch_bounds__(512, 2) void gateF(
    const float* __restrict__ X, const float* __restrict__ Wf,
    const u16* __restrict__ Wh, const u16* __restrict__ Wl,
    float* __restrict__ out) {
  __shared__ __align__(16) unsigned char smem[2 * BUFB];  // 64 KB

  const int tid = threadIdx.x;
  const int lane = tid & 63;
  const int w = tid >> 6;      // wave 0..7 -> owns tokens tok0 + w*16 ..
  const int ec = lane & 15;    // token row (A) / expert col (B)
  const int kg = lane >> 4;    // 0..3 (8 consecutive k)
  const int tok0 = blockIdx.x * 128;

  // A stream: this wave's 16 token rows
  const float* pA = X + (size_t)(tok0 + w * 16 + ec) * HD + kg * 8;

  // staging roles: wave w stages units u=2w, 2w+1; unit u = (sh=u>>2, sg=u&3)
  const int u0 = 2 * w, u1 = 2 * w + 1;
  const int sh0 = u0 >> 2, sg0 = u0 & 3;
  const int sh1 = u1 >> 2, sg1 = u1 & 3;
  const size_t wsrc0 = (size_t)(sg0 * 16 + ec) * HD + sh0 * 32 + kg * 8;
  const size_t wsrc1 = (size_t)(sg1 * 16 + ec) * HD + sh1 * 32 + kg * 8;
  // LDS dst byte offset: ((sh*2+split)*4+sg)*1024 + lane*16  (split: +4096)
  const int sdst0 = (sh0 * 8 + sg0) * 1024 + lane * 16;
  const int sdst1 = (sh1 * 8 + sg1) * 1024 + lane * 16;

  accv acc[4];
  #pragma unroll
  for (int f = 0; f < 4; ++f) acc[f] = (accv){0.f, 0.f, 0.f, 0.f};

  f4 ar[4][2];  // A raw ring, 4-step lookahead (static slots)

  // --- prologue: stage chunk 0 into buf0; prefetch A steps 0..3 ---
  {
    s8 th, tl;
    f4 r0, r1;
    if constexpr (PRE) {
      th = *(const s8*)(Wh + wsrc0);
      tl = *(const s8*)(Wl + wsrc0);
    } else {
      r0 = *(const f4*)(Wf + wsrc0);
      r1 = *(const f4*)(Wf + wsrc0 + 4);
      split8h(r0, r1, th, tl);
    }
    unsigned char* d = smem + sdst0;
    *(s8*)(d) = th;
    *(s8*)(d + 4096) = tl;
    if constexpr (PRE) {
      th = *(const s8*)(Wh + wsrc1);
      tl = *(const s8*)(Wl + wsrc1);
    } else {
      r0 = *(const f4*)(Wf + wsrc1);
      r1 = *(const f4*)(Wf + wsrc1 + 4);
      split8h(r0, r1, th, tl);
    }
    d = smem + sdst1;
    *(s8*)(d) = th;
    *(s8*)(d + 4096) = tl;
  }
  #pragma unroll
  for (int st = 0; st < 4; ++st) {
    ar[st][0] = *(const f4*)(pA + st * 32);
    ar[st][1] = *(const f4*)(pA + st * 32 + 4);
  }
  asm volatile("s_waitcnt lgkmcnt(0)");
  __builtin_amdgcn_s_barrier();
  __builtin_amdgcn_sched_barrier(0);

  // --- main loop: 16 chunks of K=128 (4 MFMA-steps each) ---
  for (int c = 0; c < NCH; ++c) {
    const unsigned char* rb = smem + (c & 1) * BUFB;
    unsigned char* wb = smem + ((c + 1) & 1) * BUFB;
    const bool do_stage = (c + 1 < NCH);

    // issue next-chunk B loads NOW (written to LDS after compute: T14 split)
    s8 th0, tl0, th1, tl1;
    f4 q00, q01, q10, q11;
    if (do_stage) {
      const size_t o0 = wsrc0 + (size_t)(c + 1) * 128;
      const size_t o1 = wsrc1 + (size_t)(c + 1) * 128;
      if constexpr (PRE) {
        th0 = *(const s8*)(Wh + o0);
        tl0 = *(const s8*)(Wl + o0);
        th1 = *(const s8*)(Wh + o1);
        tl1 = *(const s8*)(Wl + o1);
      } else {
        q00 = *(const f4*)(Wf + o0);
        q01 = *(const f4*)(Wf + o0 + 4);
        q10 = *(const f4*)(Wf + o1);
        q11 = *(const f4*)(Wf + o1 + 4);
      }
    }

    #pragma unroll
    for (int st = 0; st < 4; ++st) {
      const int t = c * 4 + st;
      s8 ah, al;
      split8h(ar[st][0], ar[st][1], ah, al);
      const int tn = (t + 4 < 64) ? (t + 4) : 63;  // clamp; dup load harmless
      ar[st][0] = *(const f4*)(pA + tn * 32);
      ar[st][1] = *(const f4*)(pA + tn * 32 + 4);
      #pragma unroll
      for (int f = 0; f < 4; ++f) {
        const unsigned char* bp = rb + st * 8192 + f * 1024 + lane * 16;
        s8 bh = *(const s8*)(bp);
        s8 bl = *(const s8*)(bp + 4096);
        acc[f] = mfma3(ah, al, bh, bl, acc[f]);
      }
    }

    // write staged B (loads have had 4 steps to land)
    if (do_stage) {
      if constexpr (!PRE) {
        split8h(q00, q01, th0, tl0);
        split8h(q10, q11, th1, tl1);
      }
      unsigned char* d = wb + sdst0;
      *(s8*)(d) = th0;
      *(s8*)(d + 4096) = tl0;
      d = wb + sdst1;
      *(s8*)(d) = th1;
      *(s8*)(d + 4096) = tl1;
    }
    // boundary: LDS-only drain; A vmcnt stream NEVER drained
    __builtin_amdgcn_sched_barrier(0);
    asm volatile("s_waitcnt lgkmcnt(0)");
    __builtin_amdgcn_s_barrier();
    __builtin_amdgcn_sched_barrier(0);
  }

  // --- epilogue: per-wave logit scatter (own region, no barrier needed) ---
  float* lf = (float*)smem + w * 1088;  // 16 tok x 68 floats
  #pragma unroll
  for (int f = 0; f < 4; ++f)
    #pragma unroll
    for (int r = 0; r < 4; ++r)
      lf[(kg * 4 + r) * 68 + f * 16 + ec] = acc[f][r];

  if (lane < 16) {
    float v[64];
    #pragma unroll
    for (int i = 0; i < 16; ++i) {
      f4 q = *(const f4*)(lf + lane * 68 + 4 * i);
      v[4 * i + 0] = q.x; v[4 * i + 1] = q.y;
      v[4 * i + 2] = q.z; v[4 * i + 3] = q.w;
    }
    epilogue64(v, out + (size_t)(tok0 + w * 16 + lane) * 6);
  }
}

extern "C" void kernel_launch(void* const* d_in, const int* in_sizes, int n_in,
                              void* d_out, int out_size, void* d_ws, size_t ws_size,
                              hipStream_t stream) {
  const float* X = (const float*)d_in[0];
  const float* Wf = (const float*)d_in[1];
  float* out = (float*)d_out;
  const int T = in_sizes[0] / HD;  // 32768
  const int nblk = T / 128;        // 256 blocks of 512 threads (8 waves)

  const size_t need = (size_t)NE * HD * sizeof(u16);  // 256 KB per split
  if (ws_size >= 2 * need) {
    u16* Whi = (u16*)d_ws;
    u16* Wlo = Whi + (size_t)NE * HD;
    cvtW2<<<dim3(64), dim3(256), 0, stream>>>(Wf, Whi, Wlo);
    gateF<true><<<dim3(nblk), dim3(512), 0, stream>>>(X, Wf, Whi, Wlo, out);
  } else {
    gateF<false><<<dim3(nblk), dim3(512), 0, stream>>>(X, Wf, nullptr, nullptr, out);
  }
}